// Round 2
// baseline (36.745 us; speedup 1.0000x reference)
//
#include <hip/hip_runtime.h>
#include <hip/hip_bf16.h>
#include <math.h>

// QuantumBottle:
// out_j = b_j + sum_{m in {1,cos,sin}^4} G_j[m] * prod_w u_w[m_w],
// u_w = (1, cos(theta_w), sin(theta_w)), theta_w = tanh(z_w)*scale.
// G derived from the fixed 2-layer Rot+CNOT unitary V via the double-angle
// identity c(t/2)^2=(1+cos t)/2, s^2=(1-cos t)/2, cs=sin(t)/2.

#define QB_S 4   // samples per thread in main kernel

// ---------------- setup kernel: build packed coefficients C[81][4] ----------------
__global__ void qb_setup(const float* __restrict__ qw,   // (2,4,3)
                         const float* __restrict__ W,    // (4,4)
                         float* __restrict__ C)          // 81*4 floats out
{
    __shared__ float Vr[16][16];
    __shared__ float Vi[16][16];
    __shared__ __align__(16) float4 sM[256];   // M_w[k,kp] packed over w
    const int tid = threadIdx.x;

    // ---- phase 1: simulate shared circuit columns (16 threads) ----
    if (tid < 16) {
        float ar[16], ai[16];
        #pragma unroll
        for (int i = 0; i < 16; ++i) { ar[i] = (i == tid) ? 1.0f : 0.0f; ai[i] = 0.0f; }

        for (int l = 0; l < 2; ++l) {
            for (int w = 0; w < 4; ++w) {
                const float phi = qw[(l * 4 + w) * 3 + 0];
                const float th  = qw[(l * 4 + w) * 3 + 1];
                const float om  = qw[(l * 4 + w) * 3 + 2];
                const float ct = cosf(0.5f * th), st = sinf(0.5f * th);
                const float hp = 0.5f * (phi + om), hm = 0.5f * (phi - om);
                const float epr = cosf(hp), epi = -sinf(hp);
                const float emr = cosf(hm), emi = -sinf(hm);
                const float u00r =  epr * ct, u00i =  epi * ct;
                const float u01r = -emr * st, u01i =  emi * st;
                const float u10r =  emr * st, u10i =  emi * st;
                const float u11r =  epr * ct, u11i = -epi * ct;
                const int bit = 1 << (3 - w);
                for (int i = 0; i < 16; ++i) {
                    if (i & bit) continue;
                    const int i1 = i | bit;
                    const float x0r = ar[i],  x0i = ai[i];
                    const float x1r = ar[i1], x1i = ai[i1];
                    ar[i]  = u00r * x0r - u00i * x0i + u01r * x1r - u01i * x1i;
                    ai[i]  = u00r * x0i + u00i * x0r + u01r * x1i + u01i * x1r;
                    ar[i1] = u10r * x0r - u10i * x0i + u11r * x1r - u11i * x1i;
                    ai[i1] = u10r * x0i + u10i * x0r + u11r * x1i + u11i * x1r;
                }
            }
            for (int w = 0; w < 4; ++w) {   // CNOT ring
                const int cb = 1 << (3 - w);
                const int tb = 1 << (3 - ((w + 1) & 3));
                for (int i = 0; i < 16; ++i) {
                    if ((i & cb) && !(i & tb)) {
                        const int i1 = i | tb;
                        float tr = ar[i]; ar[i] = ar[i1]; ar[i1] = tr;
                        float ti = ai[i]; ai[i] = ai[i1]; ai[i1] = ti;
                    }
                }
            }
        }
        #pragma unroll
        for (int i = 0; i < 16; ++i) { Vr[i][tid] = ar[i]; Vi[i][tid] = ai[i]; }
    }
    __syncthreads();

    // ---- phase 2: M_w[k,kp] = sum_i (+-)_w Re(conj(V[i,k]) V[i,kp]) (256 threads) ----
    {
        const int k = tid >> 4, kp = tid & 15;
        float m0 = 0.f, m1 = 0.f, m2 = 0.f, m3 = 0.f;
        for (int i = 0; i < 16; ++i) {
            const float pr = Vr[i][k] * Vr[i][kp] + Vi[i][k] * Vi[i][kp];
            m0 += ((i >> 3) & 1) ? -pr : pr;
            m1 += ((i >> 2) & 1) ? -pr : pr;
            m2 += ((i >> 1) & 1) ? -pr : pr;
            m3 += ( i       & 1) ? -pr : pr;
        }
        sM[tid] = make_float4(m0, m1, m2, m3);
    }
    __syncthreads();

    // ---- phase 3: G_j[m] over the 3^4 double-angle basis (81 threads) ----
    // For each m, exactly 16 (k,kp) pairs contribute, each with weight +-1/16.
    if (tid < 81) {
        const int mm[4] = { tid / 27, (tid / 9) % 3, (tid / 3) % 3, tid % 3 };
        float h0 = 0.f, h1 = 0.f, h2 = 0.f, h3 = 0.f;
        for (int t16 = 0; t16 < 16; ++t16) {
            int k = 0, kp = 0;
            float sgn = 0.0625f;
            #pragma unroll
            for (int w = 0; w < 4; ++w) {
                const int b = (t16 >> (3 - w)) & 1;
                int kw, kpw;
                if (mm[w] == 2) { kw = b; kpw = 1 - b; }
                else           { kw = b; kpw = b; if (mm[w] == 1 && b) sgn = -sgn; }
                k  |= kw  << (3 - w);
                kp |= kpw << (3 - w);
            }
            const float4 mv = sM[k * 16 + kp];
            h0 += sgn * mv.x; h1 += sgn * mv.y; h2 += sgn * mv.z; h3 += sgn * mv.w;
        }
        #pragma unroll
        for (int j = 0; j < 4; ++j) {
            C[tid * 4 + j] = W[j * 4 + 0] * h0 + W[j * 4 + 1] * h1 +
                             W[j * 4 + 2] * h2 + W[j * 4 + 3] * h3;
        }
    }
}

// ---------------- main kernel: 81-term multilinear form, QB_S samples/thread ----------------
__global__ void __launch_bounds__(256) qb_main(
    const float* __restrict__ z, const float* __restrict__ scale,
    const float* __restrict__ bias, const float* __restrict__ C,
    float* __restrict__ out, int Bn)
{
    __shared__ __align__(16) float sC[81 * 4];
    for (int i = threadIdx.x; i < 81 * 4; i += 256) sC[i] = C[i];
    __syncthreads();

    const int g      = blockIdx.x * 256 + threadIdx.x;
    const int stride = gridDim.x * 256;
    const float sc = scale[0];
    const float b0 = bias[0], b1 = bias[1], b2 = bias[2], b3 = bias[3];

    float e01[QB_S][9], e23[QB_S][9];
    bool valid[QB_S];
    #pragma unroll
    for (int s = 0; s < QB_S; ++s) {
        const int idx = g + s * stride;
        valid[s] = (idx < Bn);
        const float4 zv = valid[s] ? reinterpret_cast<const float4*>(z)[idx]
                                   : make_float4(0.f, 0.f, 0.f, 0.f);
        const float zz[4] = { zv.x, zv.y, zv.z, zv.w };
        float c[4], sn[4];
        #pragma unroll
        for (int w = 0; w < 4; ++w) {
            const float x = zz[w];
            const float e = __expf(-2.0f * fabsf(x));
            float t = __fdividef(1.0f - e, 1.0f + e);
            t = copysignf(t, x);
            __sincosf(t * sc, &sn[w], &c[w]);           // FULL angle
        }
        e01[s][0] = 1.0f;        e01[s][1] = c[1];         e01[s][2] = sn[1];
        e01[s][3] = c[0];        e01[s][4] = c[0] * c[1];  e01[s][5] = c[0] * sn[1];
        e01[s][6] = sn[0];       e01[s][7] = sn[0] * c[1]; e01[s][8] = sn[0] * sn[1];
        e23[s][0] = 1.0f;        e23[s][1] = c[3];         e23[s][2] = sn[3];
        e23[s][3] = c[2];        e23[s][4] = c[2] * c[3];  e23[s][5] = c[2] * sn[3];
        e23[s][6] = sn[2];       e23[s][7] = sn[2] * c[3]; e23[s][8] = sn[2] * sn[3];
    }

    float acc[QB_S][4];
    #pragma unroll
    for (int s = 0; s < QB_S; ++s) {
        acc[s][0] = b0; acc[s][1] = b1; acc[s][2] = b2; acc[s][3] = b3;
    }

    #pragma unroll
    for (int u = 0; u < 9; ++u) {
        #pragma unroll
        for (int v = 0; v < 9; ++v) {
            const float4 cc = reinterpret_cast<const float4*>(sC)[u * 9 + v];
            #pragma unroll
            for (int s = 0; s < QB_S; ++s) {
                const float p = e01[s][u] * e23[s][v];   // u==0/v==0 folds to copy
                acc[s][0] = fmaf(cc.x, p, acc[s][0]);
                acc[s][1] = fmaf(cc.y, p, acc[s][1]);
                acc[s][2] = fmaf(cc.z, p, acc[s][2]);
                acc[s][3] = fmaf(cc.w, p, acc[s][3]);
            }
        }
    }

    #pragma unroll
    for (int s = 0; s < QB_S; ++s) {
        const int idx = g + s * stride;
        if (valid[s])
            reinterpret_cast<float4*>(out)[idx] =
                make_float4(acc[s][0], acc[s][1], acc[s][2], acc[s][3]);
    }
}

extern "C" void kernel_launch(void* const* d_in, const int* in_sizes, int n_in,
                              void* d_out, int out_size, void* d_ws, size_t ws_size,
                              hipStream_t stream) {
    const float* z  = (const float*)d_in[0];   // (B,4)
    const float* sc = (const float*)d_in[1];   // scalar
    const float* qw = (const float*)d_in[2];   // (2,4,3)
    const float* W  = (const float*)d_in[3];   // (4,4)
    const float* bb = (const float*)d_in[4];   // (4,)
    float* out = (float*)d_out;
    float* C   = (float*)d_ws;                 // 81*4 floats of scratch

    const int Bn = in_sizes[0] / 4;
    const int threads_total = (Bn + QB_S - 1) / QB_S;
    const int blocks = (threads_total + 255) / 256;

    hipLaunchKernelGGL(qb_setup, dim3(1), dim3(256), 0, stream, qw, W, C);
    hipLaunchKernelGGL(qb_main, dim3(blocks), dim3(256), 0, stream,
                       z, sc, bb, C, out, Bn);
}

// Round 3
// 25.095 us; speedup vs baseline: 1.4642x; 1.4642x over previous
//
#include <hip/hip_runtime.h>
#include <hip/hip_bf16.h>
#include <math.h>

// QuantumBottle, fully fused single kernel.
// out_j = b_j + sum_{m in {1,cos,sin}^4} G_j[m] * prod_w u_w[m_w],
// u_w = (1, cos(theta_w), sin(theta_w)), theta_w = tanh(z_w)*scale.
// Each block redundantly builds the 81x4 coefficient table C in LDS
// (cheap: 16-state circuit sim of the shared 2-layer Rot+CNOT unitary),
// then evaluates the multilinear form for QB_S samples per thread.
// No workspace, no second kernel.

#define QB_S 4   // samples per thread

__global__ void __launch_bounds__(256) qb_fused(
    const float* __restrict__ z, const float* __restrict__ scale,
    const float* __restrict__ qw, const float* __restrict__ W,
    const float* __restrict__ bias, float* __restrict__ out, int Bn)
{
    __shared__ float sTrig[8][6];                 // per gate: ct,st,cos hp,sin hp,cos hm,sin hm
    __shared__ float Vr[16][16], Vi[16][16];      // circuit unitary columns
    __shared__ __align__(16) float4 sM[256];      // M_w[k,kp] packed over w
    __shared__ __align__(16) float sC[81 * 4];    // final coefficients

    const int tid = threadIdx.x;

    // ---- phase A1: trig table (24 threads, 1 sincos each) ----
    if (tid < 24) {
        const int g = tid / 3, which = tid % 3;
        const float phi = qw[g * 3 + 0], th = qw[g * 3 + 1], om = qw[g * 3 + 2];
        const float ang = (which == 0) ? 0.5f * th
                        : (which == 1) ? 0.5f * (phi + om)
                                       : 0.5f * (phi - om);
        sTrig[g][2 * which + 0] = cosf(ang);
        sTrig[g][2 * which + 1] = sinf(ang);
    }
    __syncthreads();

    // ---- phase A2: simulate circuit columns (16 threads) ----
    if (tid < 16) {
        float ar[16], ai[16];
        #pragma unroll
        for (int i = 0; i < 16; ++i) { ar[i] = (i == tid) ? 1.0f : 0.0f; ai[i] = 0.0f; }

        for (int l = 0; l < 2; ++l) {
            for (int w = 0; w < 4; ++w) {
                const int g = l * 4 + w;
                const float ct  = sTrig[g][0], st  = sTrig[g][1];
                const float epr = sTrig[g][2], epi = -sTrig[g][3];  // exp(-i(phi+om)/2)
                const float emr = sTrig[g][4], emi = -sTrig[g][5];  // exp(-i(phi-om)/2)
                const float u00r =  epr * ct, u00i =  epi * ct;
                const float u01r = -emr * st, u01i =  emi * st;
                const float u10r =  emr * st, u10i =  emi * st;
                const float u11r =  epr * ct, u11i = -epi * ct;
                const int bit = 1 << (3 - w);
                #pragma unroll
                for (int i = 0; i < 16; ++i) {
                    if (i & bit) continue;
                    const int i1 = i | bit;
                    const float x0r = ar[i],  x0i = ai[i];
                    const float x1r = ar[i1], x1i = ai[i1];
                    ar[i]  = u00r * x0r - u00i * x0i + u01r * x1r - u01i * x1i;
                    ai[i]  = u00r * x0i + u00i * x0r + u01r * x1i + u01i * x1r;
                    ar[i1] = u10r * x0r - u10i * x0i + u11r * x1r - u11i * x1i;
                    ai[i1] = u10r * x0i + u10i * x0r + u11r * x1i + u11i * x1r;
                }
            }
            #pragma unroll
            for (int w = 0; w < 4; ++w) {   // CNOT ring
                const int cb = 1 << (3 - w);
                const int tb = 1 << (3 - ((w + 1) & 3));
                #pragma unroll
                for (int i = 0; i < 16; ++i) {
                    if ((i & cb) && !(i & tb)) {
                        const int i1 = i | tb;
                        float tr = ar[i]; ar[i] = ar[i1]; ar[i1] = tr;
                        float ti = ai[i]; ai[i] = ai[i1]; ai[i1] = ti;
                    }
                }
            }
        }
        #pragma unroll
        for (int i = 0; i < 16; ++i) { Vr[i][tid] = ar[i]; Vi[i][tid] = ai[i]; }
    }
    __syncthreads();

    // ---- phase B: M_w[k,kp] = sum_i (+-)_w Re(conj(V[i,k]) V[i,kp]) (256 threads) ----
    {
        const int k = tid >> 4, kp = tid & 15;
        float m0 = 0.f, m1 = 0.f, m2 = 0.f, m3 = 0.f;
        #pragma unroll
        for (int i = 0; i < 16; ++i) {
            const float pr = Vr[i][k] * Vr[i][kp] + Vi[i][k] * Vi[i][kp];
            m0 += ((i >> 3) & 1) ? -pr : pr;
            m1 += ((i >> 2) & 1) ? -pr : pr;
            m2 += ((i >> 1) & 1) ? -pr : pr;
            m3 += ( i       & 1) ? -pr : pr;
        }
        sM[tid] = make_float4(m0, m1, m2, m3);
    }
    __syncthreads();

    // ---- phase C: G_j[m] over the 3^4 double-angle basis (81 threads) ----
    if (tid < 81) {
        const int mm[4] = { tid / 27, (tid / 9) % 3, (tid / 3) % 3, tid % 3 };
        float h0 = 0.f, h1 = 0.f, h2 = 0.f, h3 = 0.f;
        #pragma unroll
        for (int t16 = 0; t16 < 16; ++t16) {
            int k = 0, kp = 0;
            float sgn = 0.0625f;
            #pragma unroll
            for (int w = 0; w < 4; ++w) {
                const int b = (t16 >> (3 - w)) & 1;
                int kw, kpw;
                if (mm[w] == 2) { kw = b; kpw = 1 - b; }
                else            { kw = b; kpw = b; if (mm[w] == 1 && b) sgn = -sgn; }
                k  |= kw  << (3 - w);
                kp |= kpw << (3 - w);
            }
            const float4 mv = sM[k * 16 + kp];
            h0 += sgn * mv.x; h1 += sgn * mv.y; h2 += sgn * mv.z; h3 += sgn * mv.w;
        }
        #pragma unroll
        for (int j = 0; j < 4; ++j) {
            sC[tid * 4 + j] = W[j * 4 + 0] * h0 + W[j * 4 + 1] * h1 +
                              W[j * 4 + 2] * h2 + W[j * 4 + 3] * h3;
        }
    }
    __syncthreads();

    // ---- phase D: evaluate multilinear form, QB_S samples per thread ----
    const int g      = blockIdx.x * 256 + tid;
    const int stride = gridDim.x * 256;
    const float sc = scale[0];
    const float b0 = bias[0], b1 = bias[1], b2 = bias[2], b3 = bias[3];

    float e01[QB_S][9], e23[QB_S][9];
    bool valid[QB_S];
    #pragma unroll
    for (int s = 0; s < QB_S; ++s) {
        const int idx = g + s * stride;
        valid[s] = (idx < Bn);
        const float4 zv = valid[s] ? reinterpret_cast<const float4*>(z)[idx]
                                   : make_float4(0.f, 0.f, 0.f, 0.f);
        const float zz[4] = { zv.x, zv.y, zv.z, zv.w };
        float c[4], sn[4];
        #pragma unroll
        for (int w = 0; w < 4; ++w) {
            const float x = zz[w];
            const float e = __expf(-2.0f * fabsf(x));
            float t = __fdividef(1.0f - e, 1.0f + e);
            t = copysignf(t, x);
            __sincosf(t * sc, &sn[w], &c[w]);
        }
        e01[s][0] = 1.0f;  e01[s][1] = c[1];          e01[s][2] = sn[1];
        e01[s][3] = c[0];  e01[s][4] = c[0] * c[1];   e01[s][5] = c[0] * sn[1];
        e01[s][6] = sn[0]; e01[s][7] = sn[0] * c[1];  e01[s][8] = sn[0] * sn[1];
        e23[s][0] = 1.0f;  e23[s][1] = c[3];          e23[s][2] = sn[3];
        e23[s][3] = c[2];  e23[s][4] = c[2] * c[3];   e23[s][5] = c[2] * sn[3];
        e23[s][6] = sn[2]; e23[s][7] = sn[2] * c[3];  e23[s][8] = sn[2] * sn[3];
    }

    float acc[QB_S][4];
    #pragma unroll
    for (int s = 0; s < QB_S; ++s) {
        acc[s][0] = b0; acc[s][1] = b1; acc[s][2] = b2; acc[s][3] = b3;
    }

    #pragma unroll
    for (int u = 0; u < 9; ++u) {
        float tj[QB_S][4];
        #pragma unroll
        for (int s = 0; s < QB_S; ++s)
            tj[s][0] = tj[s][1] = tj[s][2] = tj[s][3] = 0.0f;
        #pragma unroll
        for (int v = 0; v < 9; ++v) {
            const float4 cc = reinterpret_cast<const float4*>(sC)[u * 9 + v];
            #pragma unroll
            for (int s = 0; s < QB_S; ++s) {
                const float ev = e23[s][v];
                tj[s][0] = fmaf(cc.x, ev, tj[s][0]);
                tj[s][1] = fmaf(cc.y, ev, tj[s][1]);
                tj[s][2] = fmaf(cc.z, ev, tj[s][2]);
                tj[s][3] = fmaf(cc.w, ev, tj[s][3]);
            }
        }
        #pragma unroll
        for (int s = 0; s < QB_S; ++s) {
            const float eu = e01[s][u];
            acc[s][0] = fmaf(eu, tj[s][0], acc[s][0]);
            acc[s][1] = fmaf(eu, tj[s][1], acc[s][1]);
            acc[s][2] = fmaf(eu, tj[s][2], acc[s][2]);
            acc[s][3] = fmaf(eu, tj[s][3], acc[s][3]);
        }
    }

    #pragma unroll
    for (int s = 0; s < QB_S; ++s) {
        const int idx = g + s * stride;
        if (valid[s])
            reinterpret_cast<float4*>(out)[idx] =
                make_float4(acc[s][0], acc[s][1], acc[s][2], acc[s][3]);
    }
}

extern "C" void kernel_launch(void* const* d_in, const int* in_sizes, int n_in,
                              void* d_out, int out_size, void* d_ws, size_t ws_size,
                              hipStream_t stream) {
    const float* z  = (const float*)d_in[0];   // (B,4)
    const float* sc = (const float*)d_in[1];   // scalar
    const float* qw = (const float*)d_in[2];   // (2,4,3)
    const float* W  = (const float*)d_in[3];   // (4,4)
    const float* bb = (const float*)d_in[4];   // (4,)
    float* out = (float*)d_out;

    const int Bn = in_sizes[0] / 4;
    const int threads_total = (Bn + QB_S - 1) / QB_S;
    const int blocks = (threads_total + 255) / 256;

    hipLaunchKernelGGL(qb_fused, dim3(blocks), dim3(256), 0, stream,
                       z, sc, qw, W, bb, out, Bn);
}